// Round 6
// baseline (84.083 us; speedup 1.0000x reference)
//
#include <hip/hip_runtime.h>

// Stein layer, fused single kernel, pack amortized over 2 row-groups.
// B=65536, D=32, H=128.
// out[r] = sum_k [ c_k - h_k*(h_k*c_k + v_k) ] - x.b2 + theta0
//   z = x W1 + b1 (dual-bf16 MFMA: aHi*bHi + aHi*bLo + aLo*bHi), h = tanh(z)
//   v = x W2^T (single bf16 MFMA); x.b2 via augmented col 128 of W2^T
//   c_k = sum_i W1[i,k] W2[k,i] (fp32, per-block during pack)
// Grid: 512 blocks x 256 threads (4 waves). Each block packs LDS once, then
// two 64-row groups (16 rows/wave/group), software-pipelined x prefetch.

#define NROWS 65536
#define DD 32
#define HH 128
#define NTILE 25  // 8 W1hi + 8 W1lo + 9 W2T(+b2 augmented)

typedef __attribute__((ext_vector_type(8))) short short8;
typedef __attribute__((ext_vector_type(4))) float f32x4;

static __device__ __forceinline__ unsigned short f2bf(float f) {
    unsigned u = __float_as_uint(f);
    u += 0x7fff + ((u >> 16) & 1);  // RNE
    return (unsigned short)(u >> 16);
}
static __device__ __forceinline__ float bf2f(unsigned short h) {
    return __uint_as_float(((unsigned)h) << 16);
}

// Compute one 16-row group for this wave and store 16 outputs.
static __device__ __forceinline__ void compute_group(
    const unsigned short* __restrict__ lb, const float2* __restrict__ cb,
    float th, float4 xa, float4 xb, int lane, int quad, int cl,
    float* __restrict__ outp /* = out + rowgroup base for this wave */) {
    const float xv[8] = {xa.x, xa.y, xa.z, xa.w, xb.x, xb.y, xb.z, xb.w};
    short8 aHi, aLo;
#pragma unroll
    for (int j = 0; j < 8; ++j) {
        const unsigned short h = f2bf(xv[j]);
        aHi[j] = (short)h;
        aLo[j] = (short)f2bf(xv[j] - bf2f(h));
    }

    const f32x4 zero = {0.f, 0.f, 0.f, 0.f};
    float sa[4] = {0.f, 0.f, 0.f, 0.f};
    const float C2LOG2E = 2.8853900817779268f;  // 2*log2(e)

#pragma unroll
    for (int t = 0; t < 8; ++t) {
        const short8 bH = *(const short8*)(lb + t * 512 + lane * 8);
        const short8 bL = *(const short8*)(lb + (8 + t) * 512 + lane * 8);
        const short8 bW = *(const short8*)(lb + (16 + t) * 512 + lane * 8);
        const float2 cbv = cb[t * 16 + cl];
        f32x4 z = zero;
        z = __builtin_amdgcn_mfma_f32_16x16x32_bf16(aLo, bH, z, 0, 0, 0);
        z = __builtin_amdgcn_mfma_f32_16x16x32_bf16(aHi, bL, z, 0, 0, 0);
        z = __builtin_amdgcn_mfma_f32_16x16x32_bf16(aHi, bH, z, 0, 0, 0);
        const f32x4 v = __builtin_amdgcn_mfma_f32_16x16x32_bf16(aHi, bW, zero, 0, 0, 0);
#pragma unroll
        for (int r = 0; r < 4; ++r) {
            const float zz = z[r] + cbv.y;
            // tanh(zz) = 1 - 2/(2^(zz*2log2e)+1); 2^inf->1, 2^-inf->-1: exact
            const float e = __builtin_amdgcn_exp2f(zz * C2LOG2E);
            const float h = fmaf(-2.f, __builtin_amdgcn_rcpf(e + 1.f), 1.f);
            sa[r] += cbv.x - h * fmaf(h, cbv.x, v[r]);  // c - h^2 c - h v
        }
    }
    {  // Augmented tile 24: x.b2 lands in col 128 (cl==0), others exact zero.
        const short8 bW = *(const short8*)(lb + 24 * 512 + lane * 8);
        const f32x4 v = __builtin_amdgcn_mfma_f32_16x16x32_bf16(aHi, bW, zero, 0, 0, 0);
#pragma unroll
        for (int r = 0; r < 4; ++r) sa[r] -= v[r];
    }

    // Reduce over the 16 output columns (cl bits of the lane id).
#pragma unroll
    for (int r = 0; r < 4; ++r) {
#pragma unroll
        for (int m = 1; m < 16; m <<= 1) sa[r] += __shfl_xor(sa[r], m, 64);
    }

    // C/D rows: row = quad*4 + reg -> lane cl==0 stores 4 consecutive rows.
    if (cl == 0) {
        float4 o;
        o.x = sa[0] + th;
        o.y = sa[1] + th;
        o.z = sa[2] + th;
        o.w = sa[3] + th;
        *(float4*)(outp + quad * 4) = o;
    }
}

__global__ __launch_bounds__(256, 4) void stein_fused(
    const float* __restrict__ x, const float* __restrict__ W1,
    const float* __restrict__ b1, const float* __restrict__ W2,
    const float* __restrict__ b2, const float* __restrict__ theta,
    float* __restrict__ out) {
    __shared__ unsigned short lb[NTILE * 512];  // B-frags: lb[t*512 + l*8 + j]
    __shared__ float2 cb[HH];                   // (c_k, b1_k) pairs

    const int tid = threadIdx.x;
    const int lane = tid & 63;
    const int wv = tid >> 6;  // 4 waves
    const int quad = lane >> 4;
    const int cl = lane & 15;
    const int row0 = blockIdx.x * 128 + wv * 16;  // 512 blocks * 128 rows

    // Prefetch group 0's x before the pack phase.
    const float* xr0 = x + (size_t)(row0 + cl) * DD + quad * 8;
    const float4 c0a = *(const float4*)xr0;
    const float4 c0b = *(const float4*)(xr0 + 4);

    // ---- Pack phase (identical to verified R5 layout) ----
    // Fragment addressing: tile t, col cc, k: lb[t*512 + ((k>>3)*16+cc)*8 + (k&7)]
    if (tid < 128) {
        const int n = tid;
        const int t = n >> 4, cc = n & 15;
#pragma unroll
        for (int kg = 0; kg < 4; ++kg) {
            short8 hi, lo;
#pragma unroll
            for (int j = 0; j < 8; ++j) {
                const float w = W1[(kg * 8 + j) * HH + n];
                const unsigned short h = f2bf(w);
                hi[j] = (short)h;
                lo[j] = (short)f2bf(w - bf2f(h));
            }
            *(short8*)(lb + t * 512 + (kg * 16 + cc) * 8) = hi;
            *(short8*)(lb + (8 + t) * 512 + (kg * 16 + cc) * 8) = lo;
        }
    } else {
        const int n = tid - 128;
        const int t2 = 16 + (n >> 4), cc = n & 15;
        float row[DD];
        const float4* wr = (const float4*)(W2 + n * DD);
#pragma unroll
        for (int q = 0; q < 8; ++q) {
            const float4 f = wr[q];
            row[4 * q + 0] = f.x; row[4 * q + 1] = f.y;
            row[4 * q + 2] = f.z; row[4 * q + 3] = f.w;
        }
#pragma unroll
        for (int g = 0; g < 4; ++g) {
            short8 v;
#pragma unroll
            for (int j = 0; j < 8; ++j) v[j] = (short)f2bf(row[g * 8 + j]);
            *(short8*)(lb + t2 * 512 + (g * 16 + cc) * 8) = v;
        }
        float acc = 0.f;
#pragma unroll
        for (int k = 0; k < DD; ++k) acc = fmaf(W1[k * HH + n], row[k], acc);
        cb[n] = make_float2(acc, b1[n]);
        if (n < 16) {
#pragma unroll
            for (int g = 0; g < 4; ++g) {
                short8 v;
#pragma unroll
                for (int j = 0; j < 8; ++j)
                    v[j] = (n == 0) ? (short)f2bf(b2[g * 8 + j]) : (short)0;
                *(short8*)(lb + 24 * 512 + (g * 16 + n) * 8) = v;
            }
        }
    }
    __syncthreads();

    // Prefetch group 1's x (64 rows ahead) before computing group 0.
    const float* xr1 = xr0 + 64 * DD;
    const float4 c1a = *(const float4*)xr1;
    const float4 c1b = *(const float4*)(xr1 + 4);

    const float th = theta[0];
    compute_group(lb, cb, th, c0a, c0b, lane, quad, cl, out + row0);
    compute_group(lb, cb, th, c1a, c1b, lane, quad, cl, out + row0 + 64);
}

extern "C" void kernel_launch(void* const* d_in, const int* in_sizes, int n_in,
                              void* d_out, int out_size, void* d_ws, size_t ws_size,
                              hipStream_t stream) {
    const float* x = (const float*)d_in[0];
    const float* W1 = (const float*)d_in[1];
    const float* b1 = (const float*)d_in[2];
    const float* W2 = (const float*)d_in[3];
    const float* b2 = (const float*)d_in[4];
    const float* theta = (const float*)d_in[5];
    float* out = (float*)d_out;

    stein_fused<<<NROWS / 128, 256, 0, stream>>>(x, W1, b1, W2, b2, theta, out);
}

// Round 7
// 76.846 us; speedup vs baseline: 1.0942x; 1.0942x over previous
//
#include <hip/hip_runtime.h>

// Stein layer, two-kernel, LDS-free main. B=65536, D=32, H=128.
// out[r] = sum_k [ c_k - h_k*(h_k*c_k + v_k) ] - x.b2 + theta0
//   z = x W1 + b1 (dual-bf16 MFMA: aHi*bHi + aHi*bLo + aLo*bHi), h = tanh(z)
//   v = x W2^T (single bf16 MFMA); x.b2 via augmented col 128 of W2^T
// Pack kernel writes MFMA B-fragments + (c_k,b1_k) into d_ws once; main
// kernel (2048 blocks x 128 thr, no LDS, no barrier, 24 waves/CU) reads them
// as coalesced wave-uniform dwordx4 L2-broadcast loads.

#define NROWS 65536
#define DD 32
#define HH 128
#define NTILE 25  // 8 W1hi + 8 W1lo + 9 W2T(+b2 augmented)

typedef __attribute__((ext_vector_type(8))) short short8;
typedef __attribute__((ext_vector_type(4))) float f32x4;

static __device__ __forceinline__ unsigned short f2bf(float f) {
    unsigned u = __float_as_uint(f);
    u += 0x7fff + ((u >> 16) & 1);  // RNE
    return (unsigned short)(u >> 16);
}
static __device__ __forceinline__ float bf2f(unsigned short h) {
    return __uint_as_float(((unsigned)h) << 16);
}

// Fragment addressing (verified R2/R5): packed[t*512 + l*8 + j] is
// B[k=(l>>4)*8+j][n=t*16+(l&15)] for tile t.
__global__ __launch_bounds__(256) void stein_pack(
    const float* __restrict__ W1, const float* __restrict__ W2,
    const float* __restrict__ b1, const float* __restrict__ b2,
    unsigned short* __restrict__ packed, float2* __restrict__ cb) {
    const int blk = blockIdx.x;
    if (blk < NTILE) {
        for (int idx = threadIdx.x; idx < 512; idx += 256) {
            const int l = idx >> 3, j = idx & 7;
            const int k = (l >> 4) * 8 + j;
            const int cc = l & 15;
            unsigned short val;
            if (blk < 8) {  // W1 hi
                val = f2bf(W1[k * HH + blk * 16 + cc]);
            } else if (blk < 16) {  // W1 lo residual
                const float w = W1[k * HH + (blk - 8) * 16 + cc];
                val = f2bf(w - bf2f(f2bf(w)));
            } else {  // W2T augmented: tile 24 col 128 = b2, cols 129+ = 0
                const int n = (blk - 16) * 16 + cc;
                const float w = (n < HH) ? W2[n * DD + k]
                                         : ((n == HH) ? b2[k] : 0.f);
                val = f2bf(w);
            }
            packed[blk * 512 + idx] = val;
        }
    } else {
        const int k = threadIdx.x;
        if (k < HH) {
            float acc = 0.f;
#pragma unroll
            for (int i = 0; i < DD; ++i)
                acc = fmaf(W1[i * HH + k], W2[k * DD + i], acc);
            cb[k] = make_float2(acc, b1[k]);
        }
    }
}

__global__ __launch_bounds__(128, 6) void stein_main(
    const float* __restrict__ x, const float* __restrict__ theta,
    const unsigned short* __restrict__ packed, const float2* __restrict__ cb,
    float* __restrict__ out) {
    const int tid = threadIdx.x;
    const int lane = tid & 63;
    const int wv = tid >> 6;  // 2 waves/block
    const int quad = lane >> 4;
    const int cl = lane & 15;
    const int rowbase = blockIdx.x * 32 + wv * 16;  // 2048 blocks * 32 rows

    // A fragment: A[m=cl][k=quad*8+j].
    const float* xr = x + (size_t)(rowbase + cl) * DD + quad * 8;
    const float4 x0 = *(const float4*)xr;
    const float4 x1 = *(const float4*)(xr + 4);
    const float xv[8] = {x0.x, x0.y, x0.z, x0.w, x1.x, x1.y, x1.z, x1.w};
    short8 aHi, aLo;
#pragma unroll
    for (int j = 0; j < 8; ++j) {
        const unsigned short h = f2bf(xv[j]);
        aHi[j] = (short)h;
        aLo[j] = (short)f2bf(xv[j] - bf2f(h));
    }

    const f32x4 zero = {0.f, 0.f, 0.f, 0.f};
    float sa[4] = {0.f, 0.f, 0.f, 0.f};
    const float C2LOG2E = 2.8853900817779268f;  // 2*log2(e)

#pragma unroll
    for (int t = 0; t < 8; ++t) {
        // Coalesced wave-uniform-base loads: 64 lanes x 16 B = contiguous 1 KB.
        const short8 bH = *(const short8*)(packed + t * 512 + lane * 8);
        const short8 bL = *(const short8*)(packed + (8 + t) * 512 + lane * 8);
        const short8 bW = *(const short8*)(packed + (16 + t) * 512 + lane * 8);
        const float2 cbv = cb[t * 16 + cl];
        f32x4 z = zero;
        z = __builtin_amdgcn_mfma_f32_16x16x32_bf16(aLo, bH, z, 0, 0, 0);
        z = __builtin_amdgcn_mfma_f32_16x16x32_bf16(aHi, bL, z, 0, 0, 0);
        z = __builtin_amdgcn_mfma_f32_16x16x32_bf16(aHi, bH, z, 0, 0, 0);
        const f32x4 v = __builtin_amdgcn_mfma_f32_16x16x32_bf16(aHi, bW, zero, 0, 0, 0);
#pragma unroll
        for (int r = 0; r < 4; ++r) {
            const float zz = z[r] + cbv.y;
            // tanh(zz) = 1 - 2/(2^(zz*2log2e)+1); 2^inf->1, 2^-inf->-1: exact
            const float e = __builtin_amdgcn_exp2f(zz * C2LOG2E);
            const float h = fmaf(-2.f, __builtin_amdgcn_rcpf(e + 1.f), 1.f);
            sa[r] += cbv.x - h * fmaf(h, cbv.x, v[r]);  // c - h^2 c - h v
        }
    }
    {  // Augmented tile 24: x.b2 lands in col 128 (cl==0), others exact zero.
        const short8 bW = *(const short8*)(packed + 24 * 512 + lane * 8);
        const f32x4 v = __builtin_amdgcn_mfma_f32_16x16x32_bf16(aHi, bW, zero, 0, 0, 0);
#pragma unroll
        for (int r = 0; r < 4; ++r) sa[r] -= v[r];
    }

    // Reduce over the 16 output columns (cl bits of the lane id).
#pragma unroll
    for (int r = 0; r < 4; ++r) {
#pragma unroll
        for (int m = 1; m < 16; m <<= 1) sa[r] += __shfl_xor(sa[r], m, 64);
    }

    // C/D rows: row = quad*4 + reg -> lane cl==0 stores 4 consecutive rows.
    if (cl == 0) {
        const float th = theta[0];
        float4 o;
        o.x = sa[0] + th;
        o.y = sa[1] + th;
        o.z = sa[2] + th;
        o.w = sa[3] + th;
        *(float4*)(out + rowbase + quad * 4) = o;
    }
}

extern "C" void kernel_launch(void* const* d_in, const int* in_sizes, int n_in,
                              void* d_out, int out_size, void* d_ws, size_t ws_size,
                              hipStream_t stream) {
    const float* x = (const float*)d_in[0];
    const float* W1 = (const float*)d_in[1];
    const float* b1 = (const float*)d_in[2];
    const float* W2 = (const float*)d_in[3];
    const float* b2 = (const float*)d_in[4];
    const float* theta = (const float*)d_in[5];
    float* out = (float*)d_out;

    unsigned short* packed = (unsigned short*)d_ws;      // 25*512*2 = 25600 B
    float2* cb = (float2*)((char*)d_ws + NTILE * 512 * 2);  // 128 float2

    stein_pack<<<NTILE + 1, 256, 0, stream>>>(W1, W2, b1, b2, packed, cb);
    stein_main<<<NROWS / 32, 128, 0, stream>>>(x, theta, packed, cb, out);
}

// Round 8
// 73.351 us; speedup vs baseline: 1.1463x; 1.0476x over previous
//
#include <hip/hip_runtime.h>

// Stein layer, fused single kernel (R5 structure, spill-free VGPR budget).
// B=65536, D=32, H=128.
// out[r] = sum_k [ c_k - h_k*(h_k*c_k + v_k) ] - x.b2 + theta0
//   z = x W1 + b1 (dual-bf16 MFMA: aHi*bHi + aHi*bLo + aLo*bHi), h = tanh(z)
//   v = x W2^T (single bf16 MFMA); x.b2 via augmented col 128 of W2^T
//   c_k = sum_i W1[i,k] W2[k,i] (fp32, per-block during pack)
// Grid: 1024 blocks x 256 threads (4 waves, 16 rows/wave).
// __launch_bounds__(256,4): 128 VGPR — no spill (R7's 85-VGPR cap is the
// prime suspect for its +5us; R5's 102 cap possibly marginal).

#define NROWS 65536
#define DD 32
#define HH 128
#define NTILE 25  // 8 W1hi + 8 W1lo + 9 W2T(+b2 augmented)

typedef __attribute__((ext_vector_type(8))) short short8;
typedef __attribute__((ext_vector_type(4))) float f32x4;

static __device__ __forceinline__ unsigned short f2bf(float f) {
    unsigned u = __float_as_uint(f);
    u += 0x7fff + ((u >> 16) & 1);  // RNE
    return (unsigned short)(u >> 16);
}
static __device__ __forceinline__ float bf2f(unsigned short h) {
    return __uint_as_float(((unsigned)h) << 16);
}

__global__ __launch_bounds__(256, 4) void stein_fused(
    const float* __restrict__ x, const float* __restrict__ W1,
    const float* __restrict__ b1, const float* __restrict__ W2,
    const float* __restrict__ b2, const float* __restrict__ theta,
    float* __restrict__ out) {
    __shared__ unsigned short lb[NTILE * 512];  // B-frags: lb[t*512 + l*8 + j]
    __shared__ float2 cb[HH];                   // (c_k, b1_k) pairs

    const int tid = threadIdx.x;
    const int lane = tid & 63;
    const int wv = tid >> 6;       // 4 waves
    const int quad = lane >> 4;
    const int cl = lane & 15;
    const int rowbase = blockIdx.x * 64 + wv * 16;  // 1024 blocks * 64 rows

    // Prefetch this wave's x (A[m=cl][k=quad*8+j]) and theta before the pack.
    const float* xr = x + (size_t)(rowbase + cl) * DD + quad * 8;
    const float4 x0 = *(const float4*)xr;
    const float4 x1 = *(const float4*)(xr + 4);
    const float th = theta[0];

    // ---- Pack phase (all 256 threads busy; layout verified R2..R6) ----
    // Fragment addressing: tile t, col cc, k: lb[t*512 + ((k>>3)*16+cc)*8 + (k&7)]
    if (tid < 128) {
        // W1 column n -> tiles n>>4 (hi) and 8+(n>>4) (lo), all 4 k-groups.
        const int n = tid;
        const int t = n >> 4, cc = n & 15;
#pragma unroll
        for (int kg = 0; kg < 4; ++kg) {
            short8 hi, lo;
#pragma unroll
            for (int j = 0; j < 8; ++j) {
                const float w = W1[(kg * 8 + j) * HH + n];
                const unsigned short h = f2bf(w);
                hi[j] = (short)h;
                lo[j] = (short)f2bf(w - bf2f(h));
            }
            *(short8*)(lb + t * 512 + (kg * 16 + cc) * 8) = hi;
            *(short8*)(lb + (8 + t) * 512 + (kg * 16 + cc) * 8) = lo;
        }
    } else {
        // W2 row n -> W2T column n (tile 16+(n>>4)); c_n + b1_n; tile 24.
        const int n = tid - 128;
        const int t2 = 16 + (n >> 4), cc = n & 15;
        float row[DD];
        const float4* wr = (const float4*)(W2 + n * DD);
#pragma unroll
        for (int q = 0; q < 8; ++q) {
            const float4 f = wr[q];
            row[4 * q + 0] = f.x; row[4 * q + 1] = f.y;
            row[4 * q + 2] = f.z; row[4 * q + 3] = f.w;
        }
#pragma unroll
        for (int g = 0; g < 4; ++g) {
            short8 v;
#pragma unroll
            for (int j = 0; j < 8; ++j) v[j] = (short)f2bf(row[g * 8 + j]);
            *(short8*)(lb + t2 * 512 + (g * 16 + cc) * 8) = v;
        }
        float acc = 0.f;
#pragma unroll
        for (int k = 0; k < DD; ++k) acc = fmaf(W1[k * HH + n], row[k], acc);
        cb[n] = make_float2(acc, b1[n]);
        if (n < 16) {
            // Tile 24: augmented col 128+n -> b2 (n==0) else zeros.
#pragma unroll
            for (int g = 0; g < 4; ++g) {
                short8 v;
#pragma unroll
                for (int j = 0; j < 8; ++j)
                    v[j] = (n == 0) ? (short)f2bf(b2[g * 8 + j]) : (short)0;
                *(short8*)(lb + 24 * 512 + (g * 16 + n) * 8) = v;
            }
        }
    }
    __syncthreads();

    // ---- MFMA phase ----
    const float xv[8] = {x0.x, x0.y, x0.z, x0.w, x1.x, x1.y, x1.z, x1.w};
    short8 aHi, aLo;
#pragma unroll
    for (int j = 0; j < 8; ++j) {
        const unsigned short h = f2bf(xv[j]);
        aHi[j] = (short)h;
        aLo[j] = (short)f2bf(xv[j] - bf2f(h));
    }

    const f32x4 zero = {0.f, 0.f, 0.f, 0.f};
    float sa[4] = {0.f, 0.f, 0.f, 0.f};
    const float C2LOG2E = 2.8853900817779268f;  // 2*log2(e)

#pragma unroll
    for (int t = 0; t < 8; ++t) {
        const short8 bH = *(const short8*)(lb + t * 512 + lane * 8);
        const short8 bL = *(const short8*)(lb + (8 + t) * 512 + lane * 8);
        const short8 bW = *(const short8*)(lb + (16 + t) * 512 + lane * 8);
        const float2 cbv = cb[t * 16 + cl];
        f32x4 z = zero;
        z = __builtin_amdgcn_mfma_f32_16x16x32_bf16(aLo, bH, z, 0, 0, 0);
        z = __builtin_amdgcn_mfma_f32_16x16x32_bf16(aHi, bL, z, 0, 0, 0);
        z = __builtin_amdgcn_mfma_f32_16x16x32_bf16(aHi, bH, z, 0, 0, 0);
        const f32x4 v = __builtin_amdgcn_mfma_f32_16x16x32_bf16(aHi, bW, zero, 0, 0, 0);
#pragma unroll
        for (int r = 0; r < 4; ++r) {
            const float zz = z[r] + cbv.y;
            // tanh(zz) = 1 - 2/(2^(zz*2log2e)+1); 2^inf->1, 2^-inf->-1: exact
            const float e = __builtin_amdgcn_exp2f(zz * C2LOG2E);
            const float h = fmaf(-2.f, __builtin_amdgcn_rcpf(e + 1.f), 1.f);
            sa[r] += cbv.x - h * fmaf(h, cbv.x, v[r]);  // c - h^2 c - h v
        }
    }
    {  // Augmented tile 24: x.b2 lands in col 128 (cl==0), others exact zero.
        const short8 bW = *(const short8*)(lb + 24 * 512 + lane * 8);
        const f32x4 v = __builtin_amdgcn_mfma_f32_16x16x32_bf16(aHi, bW, zero, 0, 0, 0);
#pragma unroll
        for (int r = 0; r < 4; ++r) sa[r] -= v[r];
    }

    // Reduce over the 16 output columns (cl bits of the lane id).
#pragma unroll
    for (int r = 0; r < 4; ++r) {
#pragma unroll
        for (int m = 1; m < 16; m <<= 1) sa[r] += __shfl_xor(sa[r], m, 64);
    }

    // C/D rows: row = quad*4 + reg -> lane cl==0 stores 4 consecutive rows.
    if (cl == 0) {
        float4 o;
        o.x = sa[0] + th;
        o.y = sa[1] + th;
        o.z = sa[2] + th;
        o.w = sa[3] + th;
        *(float4*)(out + rowbase + quad * 4) = o;
    }
}

extern "C" void kernel_launch(void* const* d_in, const int* in_sizes, int n_in,
                              void* d_out, int out_size, void* d_ws, size_t ws_size,
                              hipStream_t stream) {
    const float* x = (const float*)d_in[0];
    const float* W1 = (const float*)d_in[1];
    const float* b1 = (const float*)d_in[2];
    const float* W2 = (const float*)d_in[3];
    const float* b2 = (const float*)d_in[4];
    const float* theta = (const float*)d_in[5];
    float* out = (float*)d_out;

    stein_fused<<<NROWS / 64, 256, 0, stream>>>(x, W1, b1, W2, b2, theta, out);
}